// Round 18
// baseline (1935.606 us; speedup 1.0000x reference)
//
#include <hip/hip_runtime.h>

#define NB 4
#define NPTS 8192
#define CIN 64
#define COUT 128
#define NS 2048
#define KNBR 64

#define TFPS 1024
#define PPT 8               // producer: points per thread
#define NWAVE 16

#define NCONS 252
#define NWCONS (NCONS * 16) // 4032 consumer waves

__device__ __forceinline__ unsigned spread3(unsigned v) {
    v &= 0x3FFu;
    v = (v * 0x00010001u) & 0xFF0000FFu;
    v = (v * 0x00000101u) & 0x0F00F00Fu;
    v = (v * 0x00000011u) & 0xC30C30C3u;
    v = (v * 0x00000005u) & 0x49249249u;
    return v;
}

__device__ __forceinline__ unsigned quant6(float v) {
    float q = fminf(fmaxf((v + 5.0f) * 6.4f, 0.0f), 63.0f);
    return (unsigned)(int)q;
}

#define DPP_UMAX(v, ctrl)                                                     \
    {                                                                         \
        unsigned _t = (unsigned)__builtin_amdgcn_update_dpp(                  \
            (int)(v), (int)(v), (ctrl), 0xF, 0xF, false);                     \
        (v) = ((v) > _t) ? (v) : _t;                                          \
    }

#define DPP_FMAX(v, ctrl)                                                     \
    {                                                                         \
        float _t = __builtin_bit_cast(float, __builtin_amdgcn_update_dpp(     \
            __builtin_bit_cast(int, (v)), __builtin_bit_cast(int, (v)),       \
            (ctrl), 0xF, 0xF, false));                                        \
        (v) = fmaxf((v), _t);                                                 \
    }

// wave-synchronous LDS fence: drain own ds ops + compiler barrier
#define WSYNC() asm volatile("s_waitcnt lgkmcnt(0)" ::: "memory")

// Step barrier: LDS-drain ONLY (no vmcnt) + raw s_barrier (proven R16/R17).
#define STEP_BARRIER()                                                        \
    do {                                                                      \
        asm volatile("s_waitcnt lgkmcnt(0)" ::: "memory");                    \
        __builtin_amdgcn_s_barrier();                                         \
        asm volatile("" ::: "memory");                                        \
    } while (0)

// ---------------------------------------------------------------------------
// Mega-kernel (R17 base, 1430us): blocks 0..3 = FPS producers; blocks
// 4..255 = consumers (wave-per-row radius + MLP + max-pool). 1 block/CU.
// Producer change vs R17: publication carries COORDS with the key.
//  - per wave: candidate {u64 key, x,y,z} kept in registers (cndmask-tracked
//    winner coords on the active path; cached on the skip path);
//  - every wave ds_writes its candidate to keyarr/coordarr[parity][wv]
//    every step (no atomicMax, no zeroing; parity + single barrier give
//    disjoint write/read epochs);
//  - post-barrier: ONE LDS read round (b64+b128), 16-lane DPP max, ballot
//    +ffs winner lane, readlane coords. fi decode + spos[fi] read removed.
// Key semantics unchanged: u64 max == (max md, lowest index) == jnp.argmax.
// Keys unique across waves (disjoint point ownership) -> winner unambiguous.
// ---------------------------------------------------------------------------
__global__ __launch_bounds__(1024) void mega_kernel(
    const float* __restrict__ pos, const float* __restrict__ x,
    const float* __restrict__ W1, const float* __restrict__ b1,
    const float* __restrict__ W2, const float* __restrict__ b2,
    const float* __restrict__ W3, const float* __restrict__ b3,
    float* __restrict__ out, float* __restrict__ pos_s,
    unsigned long long* __restrict__ pub)    // [NB*NS*3] tagged words
{
    __shared__ __align__(16) char smem[131840];

    const int tid  = threadIdx.x;
    const int lane = tid & 63;
    const int wv   = tid >> 6;
    const int bid  = blockIdx.x;

    if (bid < NB) {
        // ================= PRODUCER: FPS for cloud `bid` =================
        float* spos = (float*)smem;                              // 96 KB
        unsigned* skey = (unsigned*)(smem + 98304);              // 32 KB
        unsigned long long (*keyarr)[16] =
            (unsigned long long (*)[16])(smem + 131072);         // 256 B
        float4 (*coordarr)[16] = (float4 (*)[16])(smem + 131328);// 512 B

        const int b = bid;
        const float* pb = pos + (size_t)b * NPTS * 3;

        for (int i = tid; i < NPTS * 3; i += TFPS) spos[i] = pb[i];
        __syncthreads();

        for (int i = tid; i < NPTS; i += TFPS) {
            unsigned qx = quant6(spos[i * 3 + 0]);
            unsigned qy = quant6(spos[i * 3 + 1]);
            unsigned qz = quant6(spos[i * 3 + 2]);
            unsigned m  = spread3(qx) | (spread3(qy) << 1) | (spread3(qz) << 2);
            skey[i] = (m << 13) | (unsigned)i;
        }
        __syncthreads();

        for (int k2 = 2; k2 <= NPTS; k2 <<= 1) {
            for (int j = k2 >> 1; j > 0; j >>= 1) {
#pragma unroll
                for (int t = 0; t < NPTS / TFPS; ++t) {
                    int i = tid + t * TFPS, ixj = i ^ j;
                    if (ixj > i) {
                        unsigned a = skey[i], c = skey[ixj];
                        bool up = ((i & k2) == 0);
                        if ((a > c) == up) { skey[i] = c; skey[ixj] = a; }
                    }
                }
                __syncthreads();
            }
        }

        float px[PPT], py[PPT], pz[PPT], md[PPT];
        unsigned oi[PPT];   // 8191 - orig_idx (bigger == lower original index)
        float mnx =  __builtin_inff(), mny =  __builtin_inff(), mnz =  __builtin_inff();
        float mxx = -__builtin_inff(), mxy = -__builtin_inff(), mxz = -__builtin_inff();
#pragma unroll
        for (int j = 0; j < PPT; ++j) {
            int o = (int)(skey[tid * PPT + j] & 8191u);
            oi[j] = 8191u - (unsigned)o;
            float xx = spos[o * 3 + 0], yy = spos[o * 3 + 1], zz = spos[o * 3 + 2];
            px[j] = xx; py[j] = yy; pz[j] = zz;
            md[j] = __builtin_inff();
            mnx = fminf(mnx, xx); mxx = fmaxf(mxx, xx);
            mny = fminf(mny, yy); mxy = fmaxf(mxy, yy);
            mnz = fminf(mnz, zz); mxz = fmaxf(mxz, zz);
        }

        if (tid == 0) {
            // one-time publication of row b*NS (consumer writes its pos_s)
            float c0 = spos[0], c1 = spos[1], c2 = spos[2];
            const unsigned grow = (unsigned)(b * NS);
            const unsigned long long tg =
                ((unsigned long long)(0xA5000000u | grow)) << 32;
            __hip_atomic_store(pub + (size_t)grow * 3 + 0, tg | __float_as_uint(c0),
                               __ATOMIC_RELAXED, __HIP_MEMORY_SCOPE_AGENT);
            __hip_atomic_store(pub + (size_t)grow * 3 + 1, tg | __float_as_uint(c1),
                               __ATOMIC_RELAXED, __HIP_MEMORY_SCOPE_AGENT);
            __hip_atomic_store(pub + (size_t)grow * 3 + 2, tg | __float_as_uint(c2),
                               __ATOMIC_RELAXED, __HIP_MEMORY_SCOPE_AGENT);
        }
        __syncthreads();

        float cx = spos[0], cy = spos[1], cz = spos[2];
        unsigned long long ckey = 0;
        float ccx = 0.0f, ccy = 0.0f, ccz = 0.0f;   // cached candidate coords
        float thr = __builtin_inff();               // forces step-1 active

        for (int s = 1; s < NS; ++s) {
            const int p = s & 1;

            float lbx = fmaxf(fmaxf(__fsub_rn(mnx, cx), __fsub_rn(cx, mxx)), 0.0f);
            float lby = fmaxf(fmaxf(__fsub_rn(mny, cy), __fsub_rn(cy, mxy)), 0.0f);
            float lbz = fmaxf(fmaxf(__fsub_rn(mnz, cz), __fsub_rn(cz, mxz)), 0.0f);
            float lb2 = lbx * lbx + lby * lby + lbz * lbz;
            bool need = (lb2 < thr);   // thr = umax * 1.0011 (conservative)

            if (__any(need)) {
                unsigned long long kb = 0;
                float bx = 0.0f, by = 0.0f, bz = 0.0f;
#pragma unroll
                for (int j = 0; j < PPT; ++j) {
                    float dx = __fsub_rn(px[j], cx);
                    float dy = __fsub_rn(py[j], cy);
                    float dz = __fsub_rn(pz[j], cz);
                    float d  = __fadd_rn(__fadd_rn(__fmul_rn(dx, dx),
                                                   __fmul_rn(dy, dy)),
                                         __fmul_rn(dz, dz));
                    float m  = fminf(md[j], d);
                    md[j] = m;
                    unsigned long long kj =
                        ((unsigned long long)__float_as_uint(m) << 32) | oi[j];
                    if (kj > kb) { kb = kj; bx = px[j]; by = py[j]; bz = pz[j]; }
                }
                thr = __uint_as_float((unsigned)(kb >> 32)) * 1.0011f;

                // wave argmax: value via DPP, subkey via ffs fast path
                unsigned vb = (unsigned)(kb >> 32), sb = (unsigned)kb;
                unsigned v = vb;
                DPP_UMAX(v, 0x111); DPP_UMAX(v, 0x112); DPP_UMAX(v, 0x114);
                DPP_UMAX(v, 0x118); DPP_UMAX(v, 0x142); DPP_UMAX(v, 0x143);
                unsigned vwav = (unsigned)__builtin_amdgcn_readlane((int)v, 63);
                unsigned long long tied = __ballot(vb == vwav);
                unsigned swav; int wl;
                if (tied & (tied - 1)) {       // >1 holder: exact subkey reduce
                    unsigned sc = (vb == vwav) ? sb : 0u;
                    DPP_UMAX(sc, 0x111); DPP_UMAX(sc, 0x112); DPP_UMAX(sc, 0x114);
                    DPP_UMAX(sc, 0x118); DPP_UMAX(sc, 0x142); DPP_UMAX(sc, 0x143);
                    swav = (unsigned)__builtin_amdgcn_readlane((int)sc, 63);
                    unsigned long long t2 = __ballot(vb == vwav && sb == swav);
                    wl = (int)__ffsll((unsigned long long)t2) - 1;
                } else {                       // unique holder
                    wl = (int)__ffsll((unsigned long long)tied) - 1;
                    swav = (unsigned)__builtin_amdgcn_readlane((int)sb, wl);
                }
                ckey = ((unsigned long long)vwav << 32) | swav;
                ccx = __uint_as_float((unsigned)__builtin_amdgcn_readlane(
                    __float_as_int(bx), wl));
                ccy = __uint_as_float((unsigned)__builtin_amdgcn_readlane(
                    __float_as_int(by), wl));
                ccz = __uint_as_float((unsigned)__builtin_amdgcn_readlane(
                    __float_as_int(bz), wl));
            }
            if (lane == 0) {
                keyarr[p][wv]   = ckey;
                coordarr[p][wv] = make_float4(ccx, ccy, ccz, 0.0f);
            }
            STEP_BARRIER();   // LDS-drain-only barrier

            // ONE read round: each lane reads slot (lane&15); 16-lane DPP max
            unsigned long long kr = keyarr[p][lane & 15];
            float4 cr = coordarr[p][lane & 15];
            unsigned vhi = (unsigned)(kr >> 32);
            DPP_UMAX(vhi, 0x111); DPP_UMAX(vhi, 0x112);
            DPP_UMAX(vhi, 0x114); DPP_UMAX(vhi, 0x118);
            unsigned vg = (unsigned)__builtin_amdgcn_readlane((int)vhi, 15);
            unsigned sc2 = ((unsigned)(kr >> 32) == vg) ? (unsigned)kr : 0u;
            DPP_UMAX(sc2, 0x111); DPP_UMAX(sc2, 0x112);
            DPP_UMAX(sc2, 0x114); DPP_UMAX(sc2, 0x118);
            unsigned sg = (unsigned)__builtin_amdgcn_readlane((int)sc2, 15);
            unsigned long long wkey = ((unsigned long long)vg << 32) | sg;
            unsigned long long wm = __ballot(kr == wkey);
            int wl2 = (int)__ffsll((unsigned long long)wm) - 1;
            cx = __uint_as_float((unsigned)__builtin_amdgcn_readlane(
                __float_as_int(cr.x), wl2));
            cy = __uint_as_float((unsigned)__builtin_amdgcn_readlane(
                __float_as_int(cr.y), wl2));
            cz = __uint_as_float((unsigned)__builtin_amdgcn_readlane(
                __float_as_int(cr.z), wl2));

            if (lane == 0 && wv >= 13) {
                // publication spread: wave 13 -> word 0, 14 -> 1, 15 -> 2
                const unsigned grow = (unsigned)(b * NS + s);
                const unsigned long long tg =
                    ((unsigned long long)(0xA5000000u | grow)) << 32;
                float c = (wv == 13) ? cx : (wv == 14) ? cy : cz;
                __hip_atomic_store(pub + (size_t)grow * 3 + (wv - 13),
                                   tg | __float_as_uint(c),
                                   __ATOMIC_RELAXED, __HIP_MEMORY_SCOPE_AGENT);
            }
        }
    } else {
        // ================= CONSUMER: wave-per-row radius + MLP ===========
        unsigned long long* wk = (unsigned long long*)smem + (size_t)wv * 1024;
        const int g = (bid - NB) * 16 + wv;          // 0..4031

        int rows[3]; int nr = 0;
        for (int r = g; r < NB * NS; r += NWCONS) rows[nr++] = r;
        if (nr >= 2 && (rows[1] & 2047) < (rows[0] & 2047)) {
            int t = rows[0]; rows[0] = rows[1]; rows[1] = t;
        }
        if (nr == 3) {
            if ((rows[2] & 2047) < (rows[1] & 2047)) {
                int t = rows[1]; rows[1] = rows[2]; rows[2] = t;
                if ((rows[1] & 2047) < (rows[0] & 2047)) {
                    t = rows[0]; rows[0] = rows[1]; rows[1] = t;
                }
            }
        }

        for (int it = 0; it < nr; ++it) {
            const int row = rows[it];
            const int b   = row >> 11;
            const unsigned tagw = 0xA5000000u | (unsigned)row;
            const unsigned long long* pr = pub + (size_t)row * 3;

            float cx, cy, cz;
            int tries = 0;
            for (;;) {
                unsigned long long w0 = __hip_atomic_load(
                    pr + 0, __ATOMIC_RELAXED, __HIP_MEMORY_SCOPE_AGENT);
                unsigned long long w1 = __hip_atomic_load(
                    pr + 1, __ATOMIC_RELAXED, __HIP_MEMORY_SCOPE_AGENT);
                unsigned long long w2 = __hip_atomic_load(
                    pr + 2, __ATOMIC_RELAXED, __HIP_MEMORY_SCOPE_AGENT);
                if ((unsigned)(w0 >> 32) == tagw && (unsigned)(w1 >> 32) == tagw &&
                    (unsigned)(w2 >> 32) == tagw) {
                    cx = __uint_as_float((unsigned)w0);
                    cy = __uint_as_float((unsigned)w1);
                    cz = __uint_as_float((unsigned)w2);
                    break;
                }
                int naps = 1 + tries; if (naps > 32) naps = 32; ++tries;
                for (int z = 0; z < naps; ++z) __builtin_amdgcn_s_sleep(64);
            }

            if (lane == 0) {
                pos_s[(size_t)row * 3 + 0] = cx;
                pos_s[(size_t)row * 3 + 1] = cy;
                pos_s[(size_t)row * 3 + 2] = cz;
            }

            const float* pb = pos + (size_t)b * NPTS * 3;
            const float R2 = (float)(0.4 * 0.4);

            unsigned cbase = 0;
            for (int t = 0; t < NPTS / 64; ++t) {
                int i = t * 64 + lane;
                float dx = __fsub_rn(pb[i * 3 + 0], cx);
                float dy = __fsub_rn(pb[i * 3 + 1], cy);
                float dz = __fsub_rn(pb[i * 3 + 2], cz);
                float d2 = __fadd_rn(__fadd_rn(__fmul_rn(dx, dx), __fmul_rn(dy, dy)),
                                     __fmul_rn(dz, dz));
                bool in = (d2 <= R2);
                unsigned long long mk = __ballot(in);
                if (in) {
                    unsigned mb = __builtin_amdgcn_mbcnt_hi(
                        (unsigned)(mk >> 32),
                        __builtin_amdgcn_mbcnt_lo((unsigned)mk, 0u));
                    unsigned p = cbase + mb;
                    if (p < 1024u)
                        wk[p] = ((unsigned long long)__float_as_uint(d2) << 32) |
                                (unsigned)i;
                }
                cbase += (unsigned)__popcll(mk);
            }
            int cnt = (int)(cbase < 1024u ? cbase : 1024u);
            WSYNC();

            if (cnt > KNBR) {
                int sz = 128; while (sz < cnt) sz <<= 1;   // 128..1024
                for (int i = cnt + lane; i < sz; i += 64) wk[i] = ~0ULL;
                WSYNC();
                for (int k2 = 2; k2 <= sz; k2 <<= 1) {
                    for (int j = k2 >> 1; j > 0; j >>= 1) {
                        for (int t = 0; t < (sz >> 6); ++t) {
                            int i = t * 64 + lane, ixj = i ^ j;
                            if (ixj > i) {
                                unsigned long long a = wk[i], c2 = wk[ixj];
                                bool up = ((i & k2) == 0);
                                if ((a > c2) == up) { wk[i] = c2; wk[ixj] = a; }
                            }
                        }
                        WSYNC();
                    }
                }
            }

            const int kn   = (cnt < KNBR) ? cnt : KNBR;
            const int slot = (lane < kn) ? lane : 0;
            const int idx  = (int)(unsigned)(wk[slot] & 0xffffffffu);

            const float* xr = x + ((size_t)b * NPTS + idx) * CIN;
            float h1[64];
#pragma unroll
            for (int o = 0; o < 64; ++o) h1[o] = b1[o];
#pragma unroll
            for (int t = 0; t < 16; ++t) {
                float4 v = *reinterpret_cast<const float4*>(xr + t * 4);
                float f0 = v.x, f1 = v.y, f2 = v.z, f3 = v.w;
#pragma unroll
                for (int o = 0; o < 64; ++o) h1[o] = fmaf(f0, W1[(t * 4 + 0) * 64 + o], h1[o]);
#pragma unroll
                for (int o = 0; o < 64; ++o) h1[o] = fmaf(f1, W1[(t * 4 + 1) * 64 + o], h1[o]);
#pragma unroll
                for (int o = 0; o < 64; ++o) h1[o] = fmaf(f2, W1[(t * 4 + 2) * 64 + o], h1[o]);
#pragma unroll
                for (int o = 0; o < 64; ++o) h1[o] = fmaf(f3, W1[(t * 4 + 3) * 64 + o], h1[o]);
            }
            {
                float r0 = pb[idx * 3 + 0] - cx;
                float r1 = pb[idx * 3 + 1] - cy;
                float r2 = pb[idx * 3 + 2] - cz;
#pragma unroll
                for (int o = 0; o < 64; ++o) h1[o] = fmaf(r0, W1[64 * 64 + o], h1[o]);
#pragma unroll
                for (int o = 0; o < 64; ++o) h1[o] = fmaf(r1, W1[65 * 64 + o], h1[o]);
#pragma unroll
                for (int o = 0; o < 64; ++o) h1[o] = fmaf(r2, W1[66 * 64 + o], h1[o]);
            }
#pragma unroll
            for (int o = 0; o < 64; ++o) h1[o] = fmaxf(h1[o], 0.0f);

            float h2[64];
#pragma unroll
            for (int o = 0; o < 64; ++o) h2[o] = b2[o];
#pragma unroll
            for (int k = 0; k < 64; ++k) {
                float f = h1[k];
#pragma unroll
                for (int o = 0; o < 64; ++o) h2[o] = fmaf(f, W2[k * 64 + o], h2[o]);
            }
#pragma unroll
            for (int o = 0; o < 64; ++o) h2[o] = fmaxf(h2[o], 0.0f);

            const bool valid = (lane < kn);
            float* orow = out + (size_t)row * COUT;
#pragma unroll
            for (int c = 0; c < 4; ++c) {
                float acc[32];
#pragma unroll
                for (int o = 0; o < 32; ++o) acc[o] = b3[c * 32 + o];
#pragma unroll
                for (int k = 0; k < 64; ++k) {
                    float f = h2[k];
#pragma unroll
                    for (int o = 0; o < 32; ++o)
                        acc[o] = fmaf(f, W3[k * 128 + c * 32 + o], acc[o]);
                }
#pragma unroll
                for (int o = 0; o < 32; ++o) {
                    float v = valid ? acc[o] : -__builtin_inff();
                    DPP_FMAX(v, 0x111); DPP_FMAX(v, 0x112); DPP_FMAX(v, 0x114);
                    DPP_FMAX(v, 0x118); DPP_FMAX(v, 0x142); DPP_FMAX(v, 0x143);
                    acc[o] = v;   // lane 63 holds the wave max
                }
                if (lane == 63) {
#pragma unroll
                    for (int q = 0; q < 8; ++q) {
                        float4 v;
                        v.x = acc[q * 4 + 0]; v.y = acc[q * 4 + 1];
                        v.z = acc[q * 4 + 2]; v.w = acc[q * 4 + 3];
                        *reinterpret_cast<float4*>(orow + c * 32 + q * 4) = v;
                    }
                }
            }
        }
    }
}

extern "C" void kernel_launch(void* const* d_in, const int* in_sizes, int n_in,
                              void* d_out, int out_size, void* d_ws, size_t ws_size,
                              hipStream_t stream)
{
    const float* x   = (const float*)d_in[0];
    const float* pos = (const float*)d_in[1];
    const float* W1  = (const float*)d_in[2];
    const float* b1  = (const float*)d_in[3];
    const float* W2  = (const float*)d_in[4];
    const float* b2  = (const float*)d_in[5];
    const float* W3  = (const float*)d_in[6];
    const float* b3  = (const float*)d_in[7];

    float* out   = (float*)d_out;
    float* pos_s = out + (size_t)NB * NS * COUT;
    unsigned long long* pub = (unsigned long long*)d_ws;   // 8192*3*8 = 196 KB

    mega_kernel<<<dim3(NB + NCONS), dim3(TFPS), 0, stream>>>(
        pos, x, W1, b1, W2, b2, W3, b3, out, pos_s, pub);
}

// Round 19
// 1426.388 us; speedup vs baseline: 1.3570x; 1.3570x over previous
//
#include <hip/hip_runtime.h>

#define NB 4
#define NPTS 8192
#define CIN 64
#define COUT 128
#define NS 2048
#define KNBR 64

#define TFPS 1024
#define PPT 8               // producer: points per thread
#define NWAVE 16

#define NCONS 252
#define NWCONS (NCONS * 16) // 4032 consumer waves

__device__ __forceinline__ unsigned spread3(unsigned v) {
    v &= 0x3FFu;
    v = (v * 0x00010001u) & 0xFF0000FFu;
    v = (v * 0x00000101u) & 0x0F00F00Fu;
    v = (v * 0x00000011u) & 0xC30C30C3u;
    v = (v * 0x00000005u) & 0x49249249u;
    return v;
}

__device__ __forceinline__ unsigned quant6(float v) {
    float q = fminf(fmaxf((v + 5.0f) * 6.4f, 0.0f), 63.0f);
    return (unsigned)(int)q;
}

#define DPP_UMAX(v, ctrl)                                                     \
    {                                                                         \
        unsigned _t = (unsigned)__builtin_amdgcn_update_dpp(                  \
            (int)(v), (int)(v), (ctrl), 0xF, 0xF, false);                     \
        (v) = ((v) > _t) ? (v) : _t;                                          \
    }

#define DPP_FMAX(v, ctrl)                                                     \
    {                                                                         \
        float _t = __builtin_bit_cast(float, __builtin_amdgcn_update_dpp(     \
            __builtin_bit_cast(int, (v)), __builtin_bit_cast(int, (v)),       \
            (ctrl), 0xF, 0xF, false));                                        \
        (v) = fmaxf((v), _t);                                                 \
    }

// wave-synchronous LDS fence: drain own ds ops + compiler barrier
#define WSYNC() asm volatile("s_waitcnt lgkmcnt(0)" ::: "memory")

// Step barrier: LDS-drain ONLY (no vmcnt) + raw s_barrier (proven R16/R17).
#define STEP_BARRIER()                                                        \
    do {                                                                      \
        asm volatile("s_waitcnt lgkmcnt(0)" ::: "memory");                    \
        __builtin_amdgcn_s_barrier();                                         \
        asm volatile("" ::: "memory");                                        \
    } while (0)

// ---------------------------------------------------------------------------
// Mega-kernel (R17, 1430us proven — exact revert after R18 regression):
// blocks 0..3 = FPS producers; blocks 4..255 = consumers (wave-per-row
// radius + MLP + max-pool). 128KB LDS -> 1 block/CU -> all 256 co-resident.
//  - producer: 1024 thr, 16 waves, 8 Morton-contiguous pts/thread, bbox
//    skip test with cached inflated threshold, u64-key update loop, DPP
//    wave argmax, 4-subslot LDS atomicMax publication, LDS-only barrier,
//    gslot zeroing on wave 1, pub stores spread on waves 13/14/15;
//  - consumers: validate tagged pub words (RELAXED agent-scope), write
//    pos_s, ballot+mbcnt radius compaction, wave-local bitonic top-64,
//    f32 fmaf MLP, DPP max-pool.
// Exactness: md updates plain sub/mul/add ((dx2+dy2)+dz2); u64-key max ==
// (max value, lowest index) == jnp.argmax; skipped updates provably fminf
// no-ops; poison never matches tags; stale replay data bit-identical.
// ---------------------------------------------------------------------------
__global__ __launch_bounds__(1024) void mega_kernel(
    const float* __restrict__ pos, const float* __restrict__ x,
    const float* __restrict__ W1, const float* __restrict__ b1,
    const float* __restrict__ W2, const float* __restrict__ b2,
    const float* __restrict__ W3, const float* __restrict__ b3,
    float* __restrict__ out, float* __restrict__ pos_s,
    unsigned long long* __restrict__ pub)    // [NB*NS*3] tagged words
{
    __shared__ __align__(16) char smem[131200];

    const int tid  = threadIdx.x;
    const int lane = tid & 63;
    const int wv   = tid >> 6;
    const int bid  = blockIdx.x;

    if (bid < NB) {
        // ================= PRODUCER: FPS for cloud `bid` =================
        float* spos = (float*)smem;                              // 96 KB
        unsigned* skey = (unsigned*)(smem + 98304);              // 32 KB
        unsigned long long (*gslot4)[4] =
            (unsigned long long (*)[4])(smem + 131072);          // 128 B

        const int b = bid;
        const float* pb = pos + (size_t)b * NPTS * 3;

        for (int i = tid; i < NPTS * 3; i += TFPS) spos[i] = pb[i];
        __syncthreads();

        for (int i = tid; i < NPTS; i += TFPS) {
            unsigned qx = quant6(spos[i * 3 + 0]);
            unsigned qy = quant6(spos[i * 3 + 1]);
            unsigned qz = quant6(spos[i * 3 + 2]);
            unsigned m  = spread3(qx) | (spread3(qy) << 1) | (spread3(qz) << 2);
            skey[i] = (m << 13) | (unsigned)i;
        }
        __syncthreads();

        for (int k2 = 2; k2 <= NPTS; k2 <<= 1) {
            for (int j = k2 >> 1; j > 0; j >>= 1) {
#pragma unroll
                for (int t = 0; t < NPTS / TFPS; ++t) {
                    int i = tid + t * TFPS, ixj = i ^ j;
                    if (ixj > i) {
                        unsigned a = skey[i], c = skey[ixj];
                        bool up = ((i & k2) == 0);
                        if ((a > c) == up) { skey[i] = c; skey[ixj] = a; }
                    }
                }
                __syncthreads();
            }
        }

        float px[PPT], py[PPT], pz[PPT], md[PPT];
        unsigned oi[PPT];   // 8191 - orig_idx (bigger == lower original index)
        float mnx =  __builtin_inff(), mny =  __builtin_inff(), mnz =  __builtin_inff();
        float mxx = -__builtin_inff(), mxy = -__builtin_inff(), mxz = -__builtin_inff();
#pragma unroll
        for (int j = 0; j < PPT; ++j) {
            int o = (int)(skey[tid * PPT + j] & 8191u);
            oi[j] = 8191u - (unsigned)o;
            float xx = spos[o * 3 + 0], yy = spos[o * 3 + 1], zz = spos[o * 3 + 2];
            px[j] = xx; py[j] = yy; pz[j] = zz;
            md[j] = __builtin_inff();
            mnx = fminf(mnx, xx); mxx = fmaxf(mxx, xx);
            mny = fminf(mny, yy); mxy = fmaxf(mxy, yy);
            mnz = fminf(mnz, zz); mxz = fmaxf(mxz, zz);
        }

        if (tid < 16) ((unsigned long long*)(smem + 131072))[tid] = 0ULL;
        if (tid == 0) {
            // one-time publication of row b*NS (its pos_s is written by the
            // consumer that owns row b*NS, from these exact bits)
            float c0 = spos[0], c1 = spos[1], c2 = spos[2];
            const unsigned grow = (unsigned)(b * NS);
            const unsigned long long tg =
                ((unsigned long long)(0xA5000000u | grow)) << 32;
            __hip_atomic_store(pub + (size_t)grow * 3 + 0, tg | __float_as_uint(c0),
                               __ATOMIC_RELAXED, __HIP_MEMORY_SCOPE_AGENT);
            __hip_atomic_store(pub + (size_t)grow * 3 + 1, tg | __float_as_uint(c1),
                               __ATOMIC_RELAXED, __HIP_MEMORY_SCOPE_AGENT);
            __hip_atomic_store(pub + (size_t)grow * 3 + 2, tg | __float_as_uint(c2),
                               __ATOMIC_RELAXED, __HIP_MEMORY_SCOPE_AGENT);
        }
        __syncthreads();

        float cx = spos[0], cy = spos[1], cz = spos[2];
        unsigned long long kb = (unsigned long long)0x7F800000u << 32;
        unsigned long long ckey = 0;
        float thr = __builtin_inff();   // forces step-1 active

        for (int s = 1; s < NS; ++s) {
            float lbx = fmaxf(fmaxf(__fsub_rn(mnx, cx), __fsub_rn(cx, mxx)), 0.0f);
            float lby = fmaxf(fmaxf(__fsub_rn(mny, cy), __fsub_rn(cy, mxy)), 0.0f);
            float lbz = fmaxf(fmaxf(__fsub_rn(mnz, cz), __fsub_rn(cz, mxz)), 0.0f);
            float lb2 = lbx * lbx + lby * lby + lbz * lbz;
            bool need = (lb2 < thr);   // thr = umax * 1.0011 (conservative)

            if (__any(need)) {
                kb = 0;
#pragma unroll
                for (int j = 0; j < PPT; ++j) {
                    float dx = __fsub_rn(px[j], cx);
                    float dy = __fsub_rn(py[j], cy);
                    float dz = __fsub_rn(pz[j], cz);
                    float d  = __fadd_rn(__fadd_rn(__fmul_rn(dx, dx),
                                                   __fmul_rn(dy, dy)),
                                         __fmul_rn(dz, dz));
                    float m  = fminf(md[j], d);
                    md[j] = m;
                    unsigned long long kj =
                        ((unsigned long long)__float_as_uint(m) << 32) | oi[j];
                    if (kj > kb) kb = kj;
                }
                thr = __uint_as_float((unsigned)(kb >> 32)) * 1.0011f;

                // wave argmax: value via DPP, subkey via ffs fast path
                unsigned vb = (unsigned)(kb >> 32), sb = (unsigned)kb;
                unsigned v = vb;
                DPP_UMAX(v, 0x111); DPP_UMAX(v, 0x112); DPP_UMAX(v, 0x114);
                DPP_UMAX(v, 0x118); DPP_UMAX(v, 0x142); DPP_UMAX(v, 0x143);
                unsigned vwav = (unsigned)__builtin_amdgcn_readlane((int)v, 63);
                unsigned long long tied = __ballot(vb == vwav);
                unsigned swav;
                if (tied & (tied - 1)) {       // >1 holder: exact subkey reduce
                    unsigned sc = (vb == vwav) ? sb : 0u;
                    DPP_UMAX(sc, 0x111); DPP_UMAX(sc, 0x112); DPP_UMAX(sc, 0x114);
                    DPP_UMAX(sc, 0x118); DPP_UMAX(sc, 0x142); DPP_UMAX(sc, 0x143);
                    swav = (unsigned)__builtin_amdgcn_readlane((int)sc, 63);
                } else {                       // unique holder: SALU pick
                    int wl = (int)__ffsll((unsigned long long)tied) - 1;
                    swav = (unsigned)__builtin_amdgcn_readlane((int)sb, wl);
                }
                ckey = ((unsigned long long)vwav << 32) | swav;
                if (lane == 0) atomicMax(&gslot4[s & 3][wv & 3], ckey);
            } else {
                if (lane == 0) atomicMax(&gslot4[s & 3][wv & 3], ckey);
            }
            if ((unsigned)(tid - 64) < 4u)          // wave 1 zeroes (s+2)&3
                gslot4[(s + 2) & 3][tid - 64] = 0ULL;
            STEP_BARRIER();   // LDS-drain-only barrier (no vmcnt wait)

            unsigned long long g0 = gslot4[s & 3][0];
            unsigned long long g1 = gslot4[s & 3][1];
            unsigned long long g2 = gslot4[s & 3][2];
            unsigned long long g3 = gslot4[s & 3][3];
            unsigned long long ga = (g1 > g0) ? g1 : g0;
            unsigned long long gb = (g3 > g2) ? g3 : g2;
            unsigned long long g  = (gb > ga) ? gb : ga;
            int fi = 8191 - (int)((unsigned)g & 8191u);

            cx = spos[fi * 3 + 0];
            cy = spos[fi * 3 + 1];
            cz = spos[fi * 3 + 2];
            if (lane == 0 && wv >= 13) {
                // publication spread: wave 13 -> word 0, 14 -> 1, 15 -> 2
                const unsigned grow = (unsigned)(b * NS + s);
                const unsigned long long tg =
                    ((unsigned long long)(0xA5000000u | grow)) << 32;
                float c = (wv == 13) ? cx : (wv == 14) ? cy : cz;
                __hip_atomic_store(pub + (size_t)grow * 3 + (wv - 13),
                                   tg | __float_as_uint(c),
                                   __ATOMIC_RELAXED, __HIP_MEMORY_SCOPE_AGENT);
            }
        }
    } else {
        // ================= CONSUMER: wave-per-row radius + MLP ===========
        unsigned long long* wk = (unsigned long long*)smem + (size_t)wv * 1024;
        const int g = (bid - NB) * 16 + wv;          // 0..4031

        int rows[3]; int nr = 0;
        for (int r = g; r < NB * NS; r += NWCONS) rows[nr++] = r;
        // process in publication (srow) order
        if (nr >= 2 && (rows[1] & 2047) < (rows[0] & 2047)) {
            int t = rows[0]; rows[0] = rows[1]; rows[1] = t;
        }
        if (nr == 3) {
            if ((rows[2] & 2047) < (rows[1] & 2047)) {
                int t = rows[1]; rows[1] = rows[2]; rows[2] = t;
                if ((rows[1] & 2047) < (rows[0] & 2047)) {
                    t = rows[0]; rows[0] = rows[1]; rows[1] = t;
                }
            }
        }

        for (int it = 0; it < nr; ++it) {
            const int row = rows[it];
            const int b   = row >> 11;
            const unsigned tagw = 0xA5000000u | (unsigned)row;
            const unsigned long long* pr = pub + (size_t)row * 3;

            float cx, cy, cz;
            int tries = 0;
            for (;;) {
                unsigned long long w0 = __hip_atomic_load(
                    pr + 0, __ATOMIC_RELAXED, __HIP_MEMORY_SCOPE_AGENT);
                unsigned long long w1 = __hip_atomic_load(
                    pr + 1, __ATOMIC_RELAXED, __HIP_MEMORY_SCOPE_AGENT);
                unsigned long long w2 = __hip_atomic_load(
                    pr + 2, __ATOMIC_RELAXED, __HIP_MEMORY_SCOPE_AGENT);
                if ((unsigned)(w0 >> 32) == tagw && (unsigned)(w1 >> 32) == tagw &&
                    (unsigned)(w2 >> 32) == tagw) {
                    cx = __uint_as_float((unsigned)w0);
                    cy = __uint_as_float((unsigned)w1);
                    cz = __uint_as_float((unsigned)w2);
                    break;
                }
                int naps = 1 + tries; if (naps > 32) naps = 32; ++tries;
                for (int z = 0; z < naps; ++z) __builtin_amdgcn_s_sleep(64);
            }

            // consumer owns the pos_s output for its row (bit-exact coords)
            if (lane == 0) {
                pos_s[(size_t)row * 3 + 0] = cx;
                pos_s[(size_t)row * 3 + 1] = cy;
                pos_s[(size_t)row * 3 + 2] = cz;
            }

            const float* pb = pos + (size_t)b * NPTS * 3;
            const float R2 = (float)(0.4 * 0.4);

            // ---- radius: ballot+mbcnt compaction into wave-local LDS ----
            unsigned cbase = 0;
            for (int t = 0; t < NPTS / 64; ++t) {
                int i = t * 64 + lane;
                float dx = __fsub_rn(pb[i * 3 + 0], cx);
                float dy = __fsub_rn(pb[i * 3 + 1], cy);
                float dz = __fsub_rn(pb[i * 3 + 2], cz);
                float d2 = __fadd_rn(__fadd_rn(__fmul_rn(dx, dx), __fmul_rn(dy, dy)),
                                     __fmul_rn(dz, dz));
                bool in = (d2 <= R2);
                unsigned long long mk = __ballot(in);
                if (in) {
                    unsigned mb = __builtin_amdgcn_mbcnt_hi(
                        (unsigned)(mk >> 32),
                        __builtin_amdgcn_mbcnt_lo((unsigned)mk, 0u));
                    unsigned p = cbase + mb;
                    if (p < 1024u)
                        wk[p] = ((unsigned long long)__float_as_uint(d2) << 32) |
                                (unsigned)i;
                }
                cbase += (unsigned)__popcll(mk);
            }
            int cnt = (int)(cbase < 1024u ? cbase : 1024u);
            WSYNC();

            // ---- top-64: wave-local bitonic sort (only when needed) ----
            if (cnt > KNBR) {
                int sz = 128; while (sz < cnt) sz <<= 1;   // 128..1024
                for (int i = cnt + lane; i < sz; i += 64) wk[i] = ~0ULL;
                WSYNC();
                for (int k2 = 2; k2 <= sz; k2 <<= 1) {
                    for (int j = k2 >> 1; j > 0; j >>= 1) {
                        for (int t = 0; t < (sz >> 6); ++t) {
                            int i = t * 64 + lane, ixj = i ^ j;
                            if (ixj > i) {
                                unsigned long long a = wk[i], c2 = wk[ixj];
                                bool up = ((i & k2) == 0);
                                if ((a > c2) == up) { wk[i] = c2; wk[ixj] = a; }
                            }
                        }
                        WSYNC();
                    }
                }
            }

            const int kn   = (cnt < KNBR) ? cnt : KNBR;
            const int slot = (lane < kn) ? lane : 0;
            const int idx  = (int)(unsigned)(wk[slot] & 0xffffffffu);

            // ---- MLP ----
            const float* xr = x + ((size_t)b * NPTS + idx) * CIN;
            float h1[64];
#pragma unroll
            for (int o = 0; o < 64; ++o) h1[o] = b1[o];
#pragma unroll
            for (int t = 0; t < 16; ++t) {
                float4 v = *reinterpret_cast<const float4*>(xr + t * 4);
                float f0 = v.x, f1 = v.y, f2 = v.z, f3 = v.w;
#pragma unroll
                for (int o = 0; o < 64; ++o) h1[o] = fmaf(f0, W1[(t * 4 + 0) * 64 + o], h1[o]);
#pragma unroll
                for (int o = 0; o < 64; ++o) h1[o] = fmaf(f1, W1[(t * 4 + 1) * 64 + o], h1[o]);
#pragma unroll
                for (int o = 0; o < 64; ++o) h1[o] = fmaf(f2, W1[(t * 4 + 2) * 64 + o], h1[o]);
#pragma unroll
                for (int o = 0; o < 64; ++o) h1[o] = fmaf(f3, W1[(t * 4 + 3) * 64 + o], h1[o]);
            }
            {
                float r0 = pb[idx * 3 + 0] - cx;
                float r1 = pb[idx * 3 + 1] - cy;
                float r2 = pb[idx * 3 + 2] - cz;
#pragma unroll
                for (int o = 0; o < 64; ++o) h1[o] = fmaf(r0, W1[64 * 64 + o], h1[o]);
#pragma unroll
                for (int o = 0; o < 64; ++o) h1[o] = fmaf(r1, W1[65 * 64 + o], h1[o]);
#pragma unroll
                for (int o = 0; o < 64; ++o) h1[o] = fmaf(r2, W1[66 * 64 + o], h1[o]);
            }
#pragma unroll
            for (int o = 0; o < 64; ++o) h1[o] = fmaxf(h1[o], 0.0f);

            float h2[64];
#pragma unroll
            for (int o = 0; o < 64; ++o) h2[o] = b2[o];
#pragma unroll
            for (int k = 0; k < 64; ++k) {
                float f = h1[k];
#pragma unroll
                for (int o = 0; o < 64; ++o) h2[o] = fmaf(f, W2[k * 64 + o], h2[o]);
            }
#pragma unroll
            for (int o = 0; o < 64; ++o) h2[o] = fmaxf(h2[o], 0.0f);

            const bool valid = (lane < kn);
            float* orow = out + (size_t)row * COUT;
#pragma unroll
            for (int c = 0; c < 4; ++c) {
                float acc[32];
#pragma unroll
                for (int o = 0; o < 32; ++o) acc[o] = b3[c * 32 + o];
#pragma unroll
                for (int k = 0; k < 64; ++k) {
                    float f = h2[k];
#pragma unroll
                    for (int o = 0; o < 32; ++o)
                        acc[o] = fmaf(f, W3[k * 128 + c * 32 + o], acc[o]);
                }
#pragma unroll
                for (int o = 0; o < 32; ++o) {
                    float v = valid ? acc[o] : -__builtin_inff();
                    DPP_FMAX(v, 0x111); DPP_FMAX(v, 0x112); DPP_FMAX(v, 0x114);
                    DPP_FMAX(v, 0x118); DPP_FMAX(v, 0x142); DPP_FMAX(v, 0x143);
                    acc[o] = v;   // lane 63 holds the wave max
                }
                if (lane == 63) {
#pragma unroll
                    for (int q = 0; q < 8; ++q) {
                        float4 v;
                        v.x = acc[q * 4 + 0]; v.y = acc[q * 4 + 1];
                        v.z = acc[q * 4 + 2]; v.w = acc[q * 4 + 3];
                        *reinterpret_cast<float4*>(orow + c * 32 + q * 4) = v;
                    }
                }
            }
        }
    }
}

extern "C" void kernel_launch(void* const* d_in, const int* in_sizes, int n_in,
                              void* d_out, int out_size, void* d_ws, size_t ws_size,
                              hipStream_t stream)
{
    const float* x   = (const float*)d_in[0];
    const float* pos = (const float*)d_in[1];
    const float* W1  = (const float*)d_in[2];
    const float* b1  = (const float*)d_in[3];
    const float* W2  = (const float*)d_in[4];
    const float* b2  = (const float*)d_in[5];
    const float* W3  = (const float*)d_in[6];
    const float* b3  = (const float*)d_in[7];

    float* out   = (float*)d_out;
    float* pos_s = out + (size_t)NB * NS * COUT;
    unsigned long long* pub = (unsigned long long*)d_ws;   // 8192*3*8 = 196 KB

    mega_kernel<<<dim3(NB + NCONS), dim3(TFPS), 0, stream>>>(
        pos, x, W1, b1, W2, b2, W3, b3, out, pos_s, pub);
}